// Round 1
// baseline (257.133 us; speedup 1.0000x reference)
//
#include <hip/hip_runtime.h>

#define BATCH 8
#define NN 4096
#define DD 512
#define KK 2048
#define NCHUNK 32
#define ROWS_PER_CHUNK (NN / NCHUNK)  // 128
#define SPLIT 16

// ---------------- col_sum partial: one block per (batch, row-chunk) ----------
__global__ __launch_bounds__(512) void colsum_partial_kernel(
    const float* __restrict__ h, double* __restrict__ partial) {
    int b = blockIdx.x / NCHUNK;
    int c = blockIdx.x % NCHUNK;
    int d = threadIdx.x;
    const float* hp = h + ((size_t)b * NN + (size_t)c * ROWS_PER_CHUNK) * DD + d;
    double acc = 0.0;
    #pragma unroll 4
    for (int n = 0; n < ROWS_PER_CHUNK; ++n) {
        acc += (double)hp[(size_t)n * DD];
    }
    partial[((size_t)b * NCHUNK + c) * DD + d] = acc;
}

__global__ __launch_bounds__(512) void colsum_reduce_kernel(
    const double* __restrict__ partial, double* __restrict__ colsum) {
    int b = blockIdx.x;
    int d = threadIdx.x;
    double acc = 0.0;
    #pragma unroll
    for (int c = 0; c < NCHUNK; ++c) acc += partial[((size_t)b * NCHUNK + c) * DD + d];
    colsum[b * DD + d] = acc;
}

// ---------------- scores: one wave (64 lanes) per row ------------------------
__global__ __launch_bounds__(256) void scores_kernel(
    const float* __restrict__ h, const double* __restrict__ colsum,
    float* __restrict__ scores) {
    int wave = threadIdx.x >> 6;
    int lane = threadIdx.x & 63;
    int r = blockIdx.x * 4 + wave;            // global row in [0, BATCH*NN)
    int b = r >> 12;                          // r / NN (NN = 4096)
    const float4* hp = (const float4*)(h + (size_t)r * DD) + lane * 2;
    float4 v0 = hp[0];
    float4 v1 = hp[1];
    const double* cs = colsum + b * DD + lane * 8;
    double acc = (double)v0.x * cs[0] + (double)v0.y * cs[1] +
                 (double)v0.z * cs[2] + (double)v0.w * cs[3] +
                 (double)v1.x * cs[4] + (double)v1.y * cs[5] +
                 (double)v1.z * cs[6] + (double)v1.w * cs[7];
    #pragma unroll
    for (int off = 32; off >= 1; off >>= 1) acc += __shfl_down(acc, off);
    if (lane == 0) scores[r] = (float)acc;
}

// ---------------- selection: rank-count with index tie-break -----------------
// keep i  iff  #{j : s_j < s_i  or (s_j == s_i and j < i)} < K
__global__ __launch_bounds__(256) void flags_kernel(
    const float* __restrict__ scores, int* __restrict__ flags) {
    __shared__ float sc[NN];
    int b = blockIdx.x / SPLIT;
    int s = blockIdx.x % SPLIT;
    const float* srow = scores + b * NN;
    for (int j = threadIdx.x; j < NN; j += 256) sc[j] = srow[j];
    __syncthreads();
    int i = s * 256 + threadIdx.x;
    float si = sc[i];
    int cnt = 0;
    #pragma unroll 4
    for (int j = 0; j < NN; ++j) {
        float sj = sc[j];
        cnt += (sj < si) ? 1 : 0;
        cnt += (sj == si && j < i) ? 1 : 0;
    }
    flags[b * NN + i] = (cnt < KK) ? 1 : 0;
}

// ---------------- compact kept flags into ascending index list ---------------
__global__ __launch_bounds__(1024) void compact_kernel(
    const int* __restrict__ flags, int* __restrict__ idx) {
    __shared__ int wtot[16];
    int b = blockIdx.x;
    int t = threadIdx.x;
    int lane = t & 63, w = t >> 6;
    const int* frow = flags + b * NN;
    int f0 = frow[t * 4 + 0];
    int f1 = frow[t * 4 + 1];
    int f2 = frow[t * 4 + 2];
    int f3 = frow[t * 4 + 3];
    int local = f0 + f1 + f2 + f3;
    // inclusive wave scan of per-thread totals
    int scan = local;
    #pragma unroll
    for (int off = 1; off < 64; off <<= 1) {
        int x = __shfl_up(scan, off);
        if (lane >= off) scan += x;
    }
    if (lane == 63) wtot[w] = scan;
    __syncthreads();
    int wbase = 0;
    for (int ww = 0; ww < w; ++ww) wbase += wtot[ww];
    int p = wbase + scan - local;  // exclusive prefix for this thread's 1st elem
    int* irow = idx + b * KK;
    if (f0) irow[p++] = t * 4 + 0;
    if (f1) irow[p++] = t * 4 + 1;
    if (f2) irow[p++] = t * 4 + 2;
    if (f3) irow[p++] = t * 4 + 3;
}

// ---------------- gathers ----------------------------------------------------
__global__ __launch_bounds__(256) void gather_h_kernel(
    const float* __restrict__ h, const int* __restrict__ idx,
    float* __restrict__ out) {
    int tid = blockIdx.x * 256 + threadIdx.x;  // float4 index, total B*K*128
    int v = tid & 127;                          // float4 within row (D/4 = 128)
    int row = tid >> 7;                         // b*K + k
    int b = row >> 11;                          // row / K (K = 2048)
    int src = idx[row];
    const float4* hp = (const float4*)h;
    ((float4*)out)[tid] = hp[((size_t)b * NN + src) * (DD / 4) + v];
}

__global__ __launch_bounds__(256) void gather_adj_kernel(
    const float* __restrict__ adj, const int* __restrict__ idx,
    float* __restrict__ out) {
    int row = blockIdx.x;                       // b*K + k
    int b = row >> 11;
    int src = idx[row];
    const float4* ap = (const float4*)adj + ((size_t)b * NN + src) * (NN / 4);
    float4* op = (float4*)out + (size_t)row * (NN / 4);
    #pragma unroll
    for (int q = 0; q < 4; ++q) {
        int v = threadIdx.x + q * 256;
        op[v] = ap[v];
    }
}

extern "C" void kernel_launch(void* const* d_in, const int* in_sizes, int n_in,
                              void* d_out, int out_size, void* d_ws, size_t ws_size,
                              hipStream_t stream) {
    const float* h   = (const float*)d_in[0];
    const float* adj = (const float*)d_in[1];
    float* out = (float*)d_out;
    char* ws = (char*)d_ws;

    double* partial = (double*)ws;                                   // 1 MiB
    double* colsum  = (double*)(ws + 1048576);                       // 32 KiB
    float*  scores  = (float*)(ws + 1048576 + 32768);                // 128 KiB
    int*    flags   = (int*)(ws + 1048576 + 32768 + 131072);         // 128 KiB
    int*    idx     = (int*)(ws + 1048576 + 32768 + 131072 + 131072);// 64 KiB

    hipLaunchKernelGGL(colsum_partial_kernel, dim3(BATCH * NCHUNK), dim3(512), 0, stream, h, partial);
    hipLaunchKernelGGL(colsum_reduce_kernel, dim3(BATCH), dim3(512), 0, stream, partial, colsum);
    hipLaunchKernelGGL(scores_kernel, dim3(BATCH * NN / 4), dim3(256), 0, stream, h, colsum, scores);
    hipLaunchKernelGGL(flags_kernel, dim3(BATCH * SPLIT), dim3(256), 0, stream, scores, flags);
    hipLaunchKernelGGL(compact_kernel, dim3(BATCH), dim3(1024), 0, stream, flags, idx);
    hipLaunchKernelGGL(gather_h_kernel, dim3(BATCH * KK * (DD / 4) / 256), dim3(256), 0, stream, h, idx, out);
    hipLaunchKernelGGL(gather_adj_kernel, dim3(BATCH * KK), dim3(256), 0, stream, adj, idx,
                       out + (size_t)BATCH * KK * DD);
}

// Round 2
// 184.299 us; speedup vs baseline: 1.3952x; 1.3952x over previous
//
#include <hip/hip_runtime.h>

#define BATCH 8
#define NN 4096
#define DD 512
#define KK 2048
#define NCHUNK 32
#define ROWS_PER_CHUNK (NN / NCHUNK)  // 128
#define SPLIT 16
#define JSPLIT 4
#define JCH (NN / JSPLIT)             // 1024
#define ADJ_BLOCKS (BATCH * KK)                       // 16384
#define H_BLOCKS (BATCH * KK * (DD / 4) / 256)        // 8192

// ---------------- col_sum partial: float4 loads, 4 row-streams per block -----
__global__ __launch_bounds__(512) void colsum_partial_kernel(
    const float* __restrict__ h, double* __restrict__ partial) {
    int b = blockIdx.x / NCHUNK;
    int c = blockIdx.x % NCHUNK;
    int c4 = threadIdx.x & 127;   // float4 column
    int rr = threadIdx.x >> 7;    // row stream 0..3
    const float4* hp = (const float4*)h +
        ((size_t)(b * NN + c * ROWS_PER_CHUNK)) * (DD / 4) + c4;
    double a0 = 0, a1 = 0, a2 = 0, a3 = 0;
    #pragma unroll 4
    for (int n = rr; n < ROWS_PER_CHUNK; n += 4) {
        float4 v = hp[(size_t)n * (DD / 4)];
        a0 += v.x; a1 += v.y; a2 += v.z; a3 += v.w;
    }
    double* pp = partial + (((size_t)(b * NCHUNK + c) * 4 + rr) * DD) + c4 * 4;
    pp[0] = a0; pp[1] = a1; pp[2] = a2; pp[3] = a3;
}

__global__ __launch_bounds__(512) void colsum_reduce_kernel(
    const double* __restrict__ partial, double* __restrict__ colsum) {
    int b = blockIdx.x;
    int d = threadIdx.x;
    double acc = 0.0;
    #pragma unroll 8
    for (int q = 0; q < NCHUNK * 4; ++q)
        acc += partial[((size_t)b * NCHUNK * 4 + q) * DD + d];
    colsum[b * DD + d] = acc;
}

// ---------------- scores: one wave (64 lanes) per row ------------------------
__global__ __launch_bounds__(256) void scores_kernel(
    const float* __restrict__ h, const double* __restrict__ colsum,
    float* __restrict__ scores) {
    int wave = threadIdx.x >> 6;
    int lane = threadIdx.x & 63;
    int r = blockIdx.x * 4 + wave;            // global row in [0, BATCH*NN)
    int b = r >> 12;                          // r / NN
    const float4* hp = (const float4*)(h + (size_t)r * DD) + lane * 2;
    float4 v0 = hp[0];
    float4 v1 = hp[1];
    const double* cs = colsum + b * DD + lane * 8;
    double acc = (double)v0.x * cs[0] + (double)v0.y * cs[1] +
                 (double)v0.z * cs[2] + (double)v0.w * cs[3] +
                 (double)v1.x * cs[4] + (double)v1.y * cs[5] +
                 (double)v1.z * cs[6] + (double)v1.w * cs[7];
    #pragma unroll
    for (int off = 32; off >= 1; off >>= 1) acc += __shfl_down(acc, off);
    if (lane == 0) scores[r] = (float)acc;
}

// ---------------- partial rank counts: j-range split 4-way -------------------
// pcount[(jc*BATCH + b)*NN + i] = #{j in chunk jc : s_j < s_i or (s_j==s_i && j<i)}
__global__ __launch_bounds__(256) void count_kernel(
    const float* __restrict__ scores, int* __restrict__ pcount) {
    __shared__ float sc[JCH];
    int blk = blockIdx.x;
    int jc = blk % JSPLIT;
    int s  = (blk / JSPLIT) % SPLIT;
    int b  = blk / (JSPLIT * SPLIT);
    const float* srow = scores + b * NN;
    for (int j = threadIdx.x; j < JCH; j += 256) sc[j] = srow[jc * JCH + j];
    __syncthreads();
    int i = s * 256 + threadIdx.x;
    float si = srow[i];
    int jbase = jc * JCH;
    int cnt = 0;
    #pragma unroll 8
    for (int jj = 0; jj < JCH; ++jj) {
        float sj = sc[jj];
        cnt += (sj < si) ? 1 : 0;
        cnt += (sj == si && (jbase + jj) < i) ? 1 : 0;
    }
    pcount[((size_t)jc * BATCH + b) * NN + i] = cnt;
}

// ---------------- compact: combine partial counts -> flags -> index list -----
__global__ __launch_bounds__(1024) void compact_kernel(
    const int* __restrict__ pcount, int* __restrict__ idx) {
    __shared__ int wtot[16];
    int b = blockIdx.x;
    int t = threadIdx.x;
    int lane = t & 63, w = t >> 6;
    int f[4];
    #pragma unroll
    for (int q = 0; q < 4; ++q) {
        int i = t * 4 + q;
        int cnt = 0;
        #pragma unroll
        for (int jc = 0; jc < JSPLIT; ++jc)
            cnt += pcount[((size_t)jc * BATCH + b) * NN + i];
        f[q] = (cnt < KK) ? 1 : 0;
    }
    int local = f[0] + f[1] + f[2] + f[3];
    int scan = local;
    #pragma unroll
    for (int off = 1; off < 64; off <<= 1) {
        int x = __shfl_up(scan, off);
        if (lane >= off) scan += x;
    }
    if (lane == 63) wtot[w] = scan;
    __syncthreads();
    int wbase = 0;
    for (int ww = 0; ww < w; ++ww) wbase += wtot[ww];
    int p = wbase + scan - local;
    int* irow = idx + b * KK;
    #pragma unroll
    for (int q = 0; q < 4; ++q) {
        if (f[q]) irow[p++] = t * 4 + q;
    }
}

// ---------------- fused gather: adj rows (16 KB each) + h rows ---------------
__global__ __launch_bounds__(256) void gather_kernel(
    const float* __restrict__ h, const float* __restrict__ adj,
    const int* __restrict__ idx, float* __restrict__ out_h,
    float* __restrict__ out_adj) {
    int bid = blockIdx.x;
    if (bid < ADJ_BLOCKS) {
        int row = bid;                          // b*K + k
        int b = row >> 11;
        int src = idx[row];
        const float4* ap = (const float4*)adj + ((size_t)b * NN + src) * (NN / 4);
        float4* op = (float4*)out_adj + (size_t)row * (NN / 4);
        #pragma unroll
        for (int q = 0; q < 4; ++q) {
            int v = threadIdx.x + q * 256;
            op[v] = ap[v];
        }
    } else {
        int tid = (bid - ADJ_BLOCKS) * 256 + threadIdx.x;  // float4 idx, B*K*128
        int v = tid & 127;
        int row = tid >> 7;
        int b = row >> 11;
        int src = idx[row];
        ((float4*)out_h)[tid] =
            ((const float4*)h)[((size_t)b * NN + src) * (DD / 4) + v];
    }
}

extern "C" void kernel_launch(void* const* d_in, const int* in_sizes, int n_in,
                              void* d_out, int out_size, void* d_ws, size_t ws_size,
                              hipStream_t stream) {
    const float* h   = (const float*)d_in[0];
    const float* adj = (const float*)d_in[1];
    float* out = (float*)d_out;
    char* ws = (char*)d_ws;

    double* partial = (double*)ws;                        // 4 MiB
    double* colsum  = (double*)(ws + 4194304);            // 32 KiB
    float*  scores  = (float*)(ws + 4194304 + 32768);     // 128 KiB
    int*    pcount  = (int*)(ws + 4194304 + 32768 + 131072);          // 512 KiB
    int*    idx     = (int*)(ws + 4194304 + 32768 + 131072 + 524288); // 64 KiB

    hipLaunchKernelGGL(colsum_partial_kernel, dim3(BATCH * NCHUNK), dim3(512), 0, stream, h, partial);
    hipLaunchKernelGGL(colsum_reduce_kernel, dim3(BATCH), dim3(512), 0, stream, partial, colsum);
    hipLaunchKernelGGL(scores_kernel, dim3(BATCH * NN / 4), dim3(256), 0, stream, h, colsum, scores);
    hipLaunchKernelGGL(count_kernel, dim3(BATCH * SPLIT * JSPLIT), dim3(256), 0, stream, scores, pcount);
    hipLaunchKernelGGL(compact_kernel, dim3(BATCH), dim3(1024), 0, stream, pcount, idx);
    hipLaunchKernelGGL(gather_kernel, dim3(ADJ_BLOCKS + H_BLOCKS), dim3(256), 0, stream,
                       h, adj, idx, out, out + (size_t)BATCH * KK * DD);
}

// Round 3
// 165.162 us; speedup vs baseline: 1.5569x; 1.1159x over previous
//
#include <hip/hip_runtime.h>

#define BATCH 8
#define NN 4096
#define DD 512
#define KK 2048
#define NCHUNK 32
#define ROWS_PER_CHUNK (NN / NCHUNK)  // 128
#define SPLIT 16
#define JSPLIT 4
#define JCH (NN / JSPLIT)             // 1024
#define ADJ_UNITS (BATCH * KK)                        // 16384
#define H_UNITS (BATCH * KK * (DD / 4) / 256)         // 8192
#define GATHER_GRID 2048

typedef float v4f __attribute__((ext_vector_type(4)));

// ---------------- col_sum partial: float4 loads, 4 row-streams per block -----
__global__ __launch_bounds__(512) void colsum_partial_kernel(
    const float* __restrict__ h, double* __restrict__ partial) {
    int b = blockIdx.x / NCHUNK;
    int c = blockIdx.x % NCHUNK;
    int c4 = threadIdx.x & 127;   // float4 column
    int rr = threadIdx.x >> 7;    // row stream 0..3
    const float4* hp = (const float4*)h +
        ((size_t)(b * NN + c * ROWS_PER_CHUNK)) * (DD / 4) + c4;
    double a0 = 0, a1 = 0, a2 = 0, a3 = 0;
    #pragma unroll 4
    for (int n = rr; n < ROWS_PER_CHUNK; n += 4) {
        float4 v = hp[(size_t)n * (DD / 4)];
        a0 += v.x; a1 += v.y; a2 += v.z; a3 += v.w;
    }
    double* pp = partial + (((size_t)(b * NCHUNK + c) * 4 + rr) * DD) + c4 * 4;
    pp[0] = a0; pp[1] = a1; pp[2] = a2; pp[3] = a3;
}

__global__ __launch_bounds__(512) void colsum_reduce_kernel(
    const double* __restrict__ partial, double* __restrict__ colsum) {
    int b = blockIdx.x;
    int d = threadIdx.x;
    double acc = 0.0;
    #pragma unroll 8
    for (int q = 0; q < NCHUNK * 4; ++q)
        acc += partial[((size_t)b * NCHUNK * 4 + q) * DD + d];
    colsum[b * DD + d] = acc;
}

// ---------------- scores: one wave (64 lanes) per row ------------------------
__global__ __launch_bounds__(256) void scores_kernel(
    const float* __restrict__ h, const double* __restrict__ colsum,
    float* __restrict__ scores) {
    int wave = threadIdx.x >> 6;
    int lane = threadIdx.x & 63;
    int r = blockIdx.x * 4 + wave;            // global row in [0, BATCH*NN)
    int b = r >> 12;                          // r / NN
    const float4* hp = (const float4*)(h + (size_t)r * DD) + lane * 2;
    float4 v0 = hp[0];
    float4 v1 = hp[1];
    const double* cs = colsum + b * DD + lane * 8;
    double acc = (double)v0.x * cs[0] + (double)v0.y * cs[1] +
                 (double)v0.z * cs[2] + (double)v0.w * cs[3] +
                 (double)v1.x * cs[4] + (double)v1.y * cs[5] +
                 (double)v1.z * cs[6] + (double)v1.w * cs[7];
    #pragma unroll
    for (int off = 32; off >= 1; off >>= 1) acc += __shfl_down(acc, off);
    if (lane == 0) scores[r] = (float)acc;
}

// ---------------- partial rank counts: j-range split 4-way -------------------
__global__ __launch_bounds__(256) void count_kernel(
    const float* __restrict__ scores, int* __restrict__ pcount) {
    __shared__ float sc[JCH];
    int blk = blockIdx.x;
    int jc = blk % JSPLIT;
    int s  = (blk / JSPLIT) % SPLIT;
    int b  = blk / (JSPLIT * SPLIT);
    const float* srow = scores + b * NN;
    for (int j = threadIdx.x; j < JCH; j += 256) sc[j] = srow[jc * JCH + j];
    __syncthreads();
    int i = s * 256 + threadIdx.x;
    float si = srow[i];
    int jbase = jc * JCH;
    int cnt = 0;
    #pragma unroll 8
    for (int jj = 0; jj < JCH; ++jj) {
        float sj = sc[jj];
        cnt += (sj < si) ? 1 : 0;
        cnt += (sj == si && (jbase + jj) < i) ? 1 : 0;
    }
    pcount[((size_t)jc * BATCH + b) * NN + i] = cnt;
}

// ---------------- compact: combine partial counts -> flags -> index list -----
__global__ __launch_bounds__(1024) void compact_kernel(
    const int* __restrict__ pcount, int* __restrict__ idx) {
    __shared__ int wtot[16];
    int b = blockIdx.x;
    int t = threadIdx.x;
    int lane = t & 63, w = t >> 6;
    int f[4];
    #pragma unroll
    for (int q = 0; q < 4; ++q) {
        int i = t * 4 + q;
        int cnt = 0;
        #pragma unroll
        for (int jc = 0; jc < JSPLIT; ++jc)
            cnt += pcount[((size_t)jc * BATCH + b) * NN + i];
        f[q] = (cnt < KK) ? 1 : 0;
    }
    int local = f[0] + f[1] + f[2] + f[3];
    int scan = local;
    #pragma unroll
    for (int off = 1; off < 64; off <<= 1) {
        int x = __shfl_up(scan, off);
        if (lane >= off) scan += x;
    }
    if (lane == 63) wtot[w] = scan;
    __syncthreads();
    int wbase = 0;
    for (int ww = 0; ww < w; ++ww) wbase += wtot[ww];
    int p = wbase + scan - local;
    int* irow = idx + b * KK;
    #pragma unroll
    for (int q = 0; q < 4; ++q) {
        if (f[q]) irow[p++] = t * 4 + q;
    }
}

// ---------------- grid-stride fused gather with non-temporal stores ----------
__global__ __launch_bounds__(256) void gather_kernel(
    const float* __restrict__ h, const float* __restrict__ adj,
    const int* __restrict__ idx, float* __restrict__ out_h,
    float* __restrict__ out_adj) {
    for (int u = blockIdx.x; u < ADJ_UNITS + H_UNITS; u += GATHER_GRID) {
        if (u < ADJ_UNITS) {
            int row = u;                        // b*K + k
            int b = row >> 11;
            int src = idx[row];
            const v4f* ap = (const v4f*)adj + ((size_t)b * NN + src) * (NN / 4);
            v4f* op = (v4f*)out_adj + (size_t)row * (NN / 4);
            #pragma unroll
            for (int q = 0; q < 4; ++q) {
                int v = threadIdx.x + q * 256;
                v4f val = ap[v];
                __builtin_nontemporal_store(val, op + v);
            }
        } else {
            int tid = (u - ADJ_UNITS) * 256 + threadIdx.x;  // float4 idx
            int v = tid & 127;
            int row = tid >> 7;
            int b = row >> 11;
            int src = idx[row];
            v4f val = ((const v4f*)h)[((size_t)b * NN + src) * (DD / 4) + v];
            __builtin_nontemporal_store(val, (v4f*)out_h + tid);
        }
    }
}

extern "C" void kernel_launch(void* const* d_in, const int* in_sizes, int n_in,
                              void* d_out, int out_size, void* d_ws, size_t ws_size,
                              hipStream_t stream) {
    const float* h   = (const float*)d_in[0];
    const float* adj = (const float*)d_in[1];
    float* out = (float*)d_out;
    char* ws = (char*)d_ws;

    double* partial = (double*)ws;                        // 4 MiB
    double* colsum  = (double*)(ws + 4194304);            // 32 KiB
    float*  scores  = (float*)(ws + 4194304 + 32768);     // 128 KiB
    int*    pcount  = (int*)(ws + 4194304 + 32768 + 131072);          // 512 KiB
    int*    idx     = (int*)(ws + 4194304 + 32768 + 131072 + 524288); // 64 KiB

    hipLaunchKernelGGL(colsum_partial_kernel, dim3(BATCH * NCHUNK), dim3(512), 0, stream, h, partial);
    hipLaunchKernelGGL(colsum_reduce_kernel, dim3(BATCH), dim3(512), 0, stream, partial, colsum);
    hipLaunchKernelGGL(scores_kernel, dim3(BATCH * NN / 4), dim3(256), 0, stream, h, colsum, scores);
    hipLaunchKernelGGL(count_kernel, dim3(BATCH * SPLIT * JSPLIT), dim3(256), 0, stream, scores, pcount);
    hipLaunchKernelGGL(compact_kernel, dim3(BATCH), dim3(1024), 0, stream, pcount, idx);
    hipLaunchKernelGGL(gather_kernel, dim3(GATHER_GRID), dim3(256), 0, stream,
                       h, adj, idx, out, out + (size_t)BATCH * KK * DD);
}

// Round 4
// 161.000 us; speedup vs baseline: 1.5971x; 1.0259x over previous
//
#include <hip/hip_runtime.h>

#define BATCH 8
#define NN 4096
#define DD 512
#define KK 2048
#define NCHUNK 32
#define ROWS_PER_CHUNK (NN / NCHUNK)  // 128
#define SPLIT 16
#define JSPLIT 8
#define JCH (NN / JSPLIT)             // 512
#define ADJ_UNITS (BATCH * KK)                        // 16384
#define H_UNITS (BATCH * KK * (DD / 4) / 256)         // 8192
#define GATHER_GRID 2048

typedef float v4f __attribute__((ext_vector_type(4)));

// ---------------- col_sum partial: float4 loads, 4 row-streams per block -----
__global__ __launch_bounds__(512) void colsum_partial_kernel(
    const float* __restrict__ h, double* __restrict__ partial) {
    int b = blockIdx.x / NCHUNK;
    int c = blockIdx.x % NCHUNK;
    int c4 = threadIdx.x & 127;   // float4 column
    int rr = threadIdx.x >> 7;    // row stream 0..3
    const float4* hp = (const float4*)h +
        ((size_t)(b * NN + c * ROWS_PER_CHUNK)) * (DD / 4) + c4;
    double a0 = 0, a1 = 0, a2 = 0, a3 = 0;
    #pragma unroll 4
    for (int n = rr; n < ROWS_PER_CHUNK; n += 4) {
        float4 v = hp[(size_t)n * (DD / 4)];
        a0 += v.x; a1 += v.y; a2 += v.z; a3 += v.w;
    }
    double* pp = partial + (((size_t)(b * NCHUNK + c) * 4 + rr) * DD) + c4 * 4;
    pp[0] = a0; pp[1] = a1; pp[2] = a2; pp[3] = a3;
}

__global__ __launch_bounds__(512) void colsum_reduce_kernel(
    const double* __restrict__ partial, double* __restrict__ colsum) {
    int b = blockIdx.x;
    int d = threadIdx.x;
    double acc = 0.0;
    #pragma unroll 8
    for (int q = 0; q < NCHUNK * 4; ++q)
        acc += partial[((size_t)b * NCHUNK * 4 + q) * DD + d];
    colsum[b * DD + d] = acc;
}

// ---------------- scores: one wave (64 lanes) per row ------------------------
__global__ __launch_bounds__(256) void scores_kernel(
    const float* __restrict__ h, const double* __restrict__ colsum,
    float* __restrict__ scores) {
    int wave = threadIdx.x >> 6;
    int lane = threadIdx.x & 63;
    int r = blockIdx.x * 4 + wave;            // global row in [0, BATCH*NN)
    int b = r >> 12;                          // r / NN
    const float4* hp = (const float4*)(h + (size_t)r * DD) + lane * 2;
    float4 v0 = hp[0];
    float4 v1 = hp[1];
    const double* cs = colsum + b * DD + lane * 8;
    double acc = (double)v0.x * cs[0] + (double)v0.y * cs[1] +
                 (double)v0.z * cs[2] + (double)v0.w * cs[3] +
                 (double)v1.x * cs[4] + (double)v1.y * cs[5] +
                 (double)v1.z * cs[6] + (double)v1.w * cs[7];
    #pragma unroll
    for (int off = 32; off >= 1; off >>= 1) acc += __shfl_down(acc, off);
    if (lane == 0) scores[r] = (float)acc;
}

// ---------------- partial rank counts: j-range split 8-way, float4 LDS -------
__global__ __launch_bounds__(256) void count_kernel(
    const float* __restrict__ scores, int* __restrict__ pcount) {
    __shared__ float sc[JCH];
    int blk = blockIdx.x;
    int jc = blk % JSPLIT;
    int s  = (blk / JSPLIT) % SPLIT;
    int b  = blk / (JSPLIT * SPLIT);
    const float* srow = scores + b * NN;
    for (int j = threadIdx.x; j < JCH; j += 256) sc[j] = srow[jc * JCH + j];
    __syncthreads();
    int i = s * 256 + threadIdx.x;
    float si = srow[i];
    int jbase = jc * JCH;
    int cnt = 0;
    const float4* sc4 = (const float4*)sc;
    #pragma unroll 4
    for (int jj = 0; jj < JCH / 4; ++jj) {
        float4 sv = sc4[jj];
        int j0 = jbase + jj * 4;
        cnt += (sv.x < si || (sv.x == si && (j0 + 0) < i)) ? 1 : 0;
        cnt += (sv.y < si || (sv.y == si && (j0 + 1) < i)) ? 1 : 0;
        cnt += (sv.z < si || (sv.z == si && (j0 + 2) < i)) ? 1 : 0;
        cnt += (sv.w < si || (sv.w == si && (j0 + 3) < i)) ? 1 : 0;
    }
    pcount[((size_t)jc * BATCH + b) * NN + i] = cnt;
}

// ---------------- compact: combine partial counts -> flags -> index list -----
__global__ __launch_bounds__(1024) void compact_kernel(
    const int* __restrict__ pcount, int* __restrict__ idx) {
    __shared__ int wtot[16];
    int b = blockIdx.x;
    int t = threadIdx.x;
    int lane = t & 63, w = t >> 6;
    int f[4];
    #pragma unroll
    for (int q = 0; q < 4; ++q) {
        int i = t * 4 + q;
        int cnt = 0;
        #pragma unroll
        for (int jc = 0; jc < JSPLIT; ++jc)
            cnt += pcount[((size_t)jc * BATCH + b) * NN + i];
        f[q] = (cnt < KK) ? 1 : 0;
    }
    int local = f[0] + f[1] + f[2] + f[3];
    int scan = local;
    #pragma unroll
    for (int off = 1; off < 64; off <<= 1) {
        int x = __shfl_up(scan, off);
        if (lane >= off) scan += x;
    }
    if (lane == 63) wtot[w] = scan;
    __syncthreads();
    int wbase = 0;
    for (int ww = 0; ww < w; ++ww) wbase += wtot[ww];
    int p = wbase + scan - local;
    int* irow = idx + b * KK;
    #pragma unroll
    for (int q = 0; q < 4; ++q) {
        if (f[q]) irow[p++] = t * 4 + q;
    }
}

// ---------------- grid-stride fused gather: NT loads (adj) + NT stores -------
__global__ __launch_bounds__(256) void gather_kernel(
    const float* __restrict__ h, const float* __restrict__ adj,
    const int* __restrict__ idx, float* __restrict__ out_h,
    float* __restrict__ out_adj) {
    for (int u = blockIdx.x; u < ADJ_UNITS + H_UNITS; u += GATHER_GRID) {
        if (u < ADJ_UNITS) {
            int row = u;                        // b*K + k
            int b = row >> 11;
            int src = idx[row];
            const v4f* ap = (const v4f*)adj + ((size_t)b * NN + src) * (NN / 4);
            v4f* op = (v4f*)out_adj + (size_t)row * (NN / 4);
            #pragma unroll
            for (int q = 0; q < 4; ++q) {
                int v = threadIdx.x + q * 256;
                v4f val = __builtin_nontemporal_load(ap + v);  // read-once: bypass cache
                __builtin_nontemporal_store(val, op + v);
            }
        } else {
            int tid = (u - ADJ_UNITS) * 256 + threadIdx.x;  // float4 idx
            int v = tid & 127;
            int row = tid >> 7;
            int b = row >> 11;
            int src = idx[row];
            v4f val = ((const v4f*)h)[((size_t)b * NN + src) * (DD / 4) + v];
            __builtin_nontemporal_store(val, (v4f*)out_h + tid);
        }
    }
}

extern "C" void kernel_launch(void* const* d_in, const int* in_sizes, int n_in,
                              void* d_out, int out_size, void* d_ws, size_t ws_size,
                              hipStream_t stream) {
    const float* h   = (const float*)d_in[0];
    const float* adj = (const float*)d_in[1];
    float* out = (float*)d_out;
    char* ws = (char*)d_ws;

    double* partial = (double*)ws;                        // 4 MiB
    double* colsum  = (double*)(ws + 4194304);            // 32 KiB
    float*  scores  = (float*)(ws + 4194304 + 32768);     // 128 KiB
    int*    pcount  = (int*)(ws + 4194304 + 32768 + 131072);           // 1 MiB
    int*    idx     = (int*)(ws + 4194304 + 32768 + 131072 + 1048576); // 64 KiB

    hipLaunchKernelGGL(colsum_partial_kernel, dim3(BATCH * NCHUNK), dim3(512), 0, stream, h, partial);
    hipLaunchKernelGGL(colsum_reduce_kernel, dim3(BATCH), dim3(512), 0, stream, partial, colsum);
    hipLaunchKernelGGL(scores_kernel, dim3(BATCH * NN / 4), dim3(256), 0, stream, h, colsum, scores);
    hipLaunchKernelGGL(count_kernel, dim3(BATCH * SPLIT * JSPLIT), dim3(256), 0, stream, scores, pcount);
    hipLaunchKernelGGL(compact_kernel, dim3(BATCH), dim3(1024), 0, stream, pcount, idx);
    hipLaunchKernelGGL(gather_kernel, dim3(GATHER_GRID), dim3(256), 0, stream,
                       h, adj, idx, out, out + (size_t)BATCH * KK * DD);
}